// Round 1
// baseline (577.072 us; speedup 1.0000x reference)
//
#include <hip/hip_runtime.h>
#include <cstdint>

#pragma clang fp contract(off)

#define BB 64
#define PP 32768
#define OO 50
#define THRESH_F 0.5f
#define VAR0 0.1f
#define VAR1 0.2f
#define NEGPOS_I 3

// IoU between truth (point form t0..t3) and prior point-form box (b0..b3, areaB
// precomputed from point form, matching reference arithmetic exactly).
__device__ __forceinline__ float iou_tp(float t0, float t1, float t2, float t3,
                                        float b0, float b1, float b2, float b3,
                                        float areaB) {
    float ltx = fmaxf(t0, b0), lty = fmaxf(t1, b1);
    float rbx = fminf(t2, b2), rby = fminf(t3, b3);
    float wx = fmaxf(rbx - ltx, 0.0f), wy = fmaxf(rby - lty, 0.0f);
    float inter = wx * wy;
    float areaA = (t2 - t0) * (t3 - t1);
    return inter / (areaA + areaB - inter);
}

// K1a: for every (b, p): max / first-argmax of IoU over the O truths.
__global__ void k_prior_best(const float* __restrict__ priors,
                             const float* __restrict__ targets,
                             float* __restrict__ bto, int* __restrict__ bti) {
    __shared__ float tr[OO * 4];
    int b = blockIdx.y;
    for (int i = threadIdx.x; i < OO * 4; i += blockDim.x) {
        int t = i >> 2, c = i & 3;
        tr[i] = targets[(size_t)(b * OO + t) * 5 + c];
    }
    __syncthreads();
    int p = blockIdx.x * blockDim.x + threadIdx.x;
    float4 pr = ((const float4*)priors)[p];
    float b0 = pr.x - pr.z * 0.5f, b1 = pr.y - pr.w * 0.5f;
    float b2 = pr.x + pr.z * 0.5f, b3 = pr.y + pr.w * 0.5f;
    float areaB = (b2 - b0) * (b3 - b1);
    float best = -1.0f; int bidx = 0;
    for (int t = 0; t < OO; ++t) {
        float v = iou_tp(tr[t * 4], tr[t * 4 + 1], tr[t * 4 + 2], tr[t * 4 + 3],
                         b0, b1, b2, b3, areaB);
        if (v > best) { best = v; bidx = t; }   // first-max: strict >
    }
    bto[(size_t)b * PP + p] = best;
    bti[(size_t)b * PP + p] = bidx;
}

// K1b: for every (b, t): argmax of IoU over the P priors (first index on ties).
__global__ void k_truth_best(const float* __restrict__ priors,
                             const float* __restrict__ targets,
                             int* __restrict__ bpi) {
    int b = blockIdx.y, t = blockIdx.x, tid = threadIdx.x;
    const float* tb = &targets[(size_t)(b * OO + t) * 5];
    float t0 = tb[0], t1 = tb[1], t2 = tb[2], t3 = tb[3];
    float best = -1.0f; int bidx = PP;   // PP > any real index
    for (int p = tid; p < PP; p += blockDim.x) {
        float4 pr = ((const float4*)priors)[p];
        float b0 = pr.x - pr.z * 0.5f, b1 = pr.y - pr.w * 0.5f;
        float b2 = pr.x + pr.z * 0.5f, b3 = pr.y + pr.w * 0.5f;
        float areaB = (b2 - b0) * (b3 - b1);
        float v = iou_tp(t0, t1, t2, t3, b0, b1, b2, b3, areaB);
        if (v > best || (v == best && p < bidx)) { best = v; bidx = p; }
    }
    __shared__ float sv[256]; __shared__ int si[256];
    sv[tid] = best; si[tid] = bidx;
    __syncthreads();
    for (int s = 128; s > 0; s >>= 1) {
        if (tid < s) {
            if (sv[tid + s] > sv[tid] ||
                (sv[tid + s] == sv[tid] && si[tid + s] < si[tid])) {
                sv[tid] = sv[tid + s]; si[tid] = si[tid + s];
            }
        }
        __syncthreads();
    }
    if (tid == 0) bpi[b * OO + t] = si[0];
}

// K2: forced match — sequential per batch, last write wins (mirrors jnp scatter).
__global__ void k_force(const int* __restrict__ bpi,
                        float* __restrict__ bto, int* __restrict__ bti) {
    int b = blockIdx.x;
    if (threadIdx.x == 0) {
        for (int j = 0; j < OO; ++j) {
            int p = bpi[b * OO + j];
            bto[(size_t)b * PP + p] = 2.0f;
            bti[(size_t)b * PP + p] = j;
        }
    }
}

// K3: per-batch: conf, encode, smooth-L1, lc, lc_mine; deterministic block sums.
__global__ void k_loss(const float* __restrict__ arm_loc,
                       const float* __restrict__ arm_conf,
                       const float* __restrict__ priors,
                       const float* __restrict__ targets,
                       const float* __restrict__ bto, const int* __restrict__ bti,
                       float* __restrict__ lcm, float* __restrict__ stats,
                       int* __restrict__ nposa) {
    int b = blockIdx.x, tid = threadIdx.x, nt = blockDim.x;
    float ll = 0.0f, plc = 0.0f; int np = 0;
    for (int p = tid; p < PP; p += nt) {
        size_t bp = (size_t)b * PP + p;
        float ovl = bto[bp];
        int ti = bti[bp];
        const float* tb = &targets[(size_t)(b * OO + ti) * 5];
        int label = (tb[4] >= 0.0f) ? 1 : 0;
        int conf = (ovl < THRESH_F) ? 0 : label;
        float c0 = arm_conf[bp * 2 + 0], c1 = arm_conf[bp * 2 + 1];
        float m = fmaxf(c0, c1);
        float lse = logf(expf(c0 - m) + expf(c1 - m)) + m;
        float picked = (conf == 1) ? c1 : c0;
        float lc = lse - picked;
        bool pos = conf > 0;
        lcm[bp] = pos ? 0.0f : lc;
        if (pos) {
            np++; plc += lc;
            float4 pr = ((const float4*)priors)[p];
            float gx = ((tb[0] + tb[2]) * 0.5f - pr.x) / (VAR0 * pr.z);
            float gy = ((tb[1] + tb[3]) * 0.5f - pr.y) / (VAR0 * pr.w);
            float gw = logf((tb[2] - tb[0]) / pr.z) / VAR1;
            float gh = logf((tb[3] - tb[1]) / pr.w) / VAR1;
            float g[4] = {gx, gy, gw, gh};
            const float* ld = &arm_loc[bp * 4];
            for (int c = 0; c < 4; ++c) {
                float d = ld[c] - g[c];
                float ad = fabsf(d);
                ll += (ad < 1.0f) ? 0.5f * d * d : ad - 0.5f;
            }
        }
    }
    __shared__ float s1[256], s2[256]; __shared__ int s3[256];
    s1[tid] = ll; s2[tid] = plc; s3[tid] = np;
    __syncthreads();
    for (int s = 128; s > 0; s >>= 1) {
        if (tid < s) { s1[tid] += s1[tid + s]; s2[tid] += s2[tid + s]; s3[tid] += s3[tid + s]; }
        __syncthreads();
    }
    if (tid == 0) { stats[b * 2 + 0] = s1[0]; stats[b * 2 + 1] = s2[0]; nposa[b] = s3[0]; }
}

// K4: per-batch exact top-k sum of lc_mine via 4x8-bit radix select on float bits
// (all values >= +0, so uint order == float order). Tie-exact: sum of top-k by
// value is invariant to tie choice, matching the reference's rank selection.
__global__ void k_topk(const float* __restrict__ lcm, const int* __restrict__ nposa,
                       float* __restrict__ topk) {
    int b = blockIdx.x, tid = threadIdx.x;
    int np = nposa[b];
    int k = NEGPOS_I * np; if (k > PP - 1) k = PP - 1;
    if (k <= 0) { if (tid == 0) topk[b] = 0.0f; return; }
    const float* v = lcm + (size_t)b * PP;
    __shared__ int hist[256];
    __shared__ unsigned s_prefix; __shared__ int s_rem;
    if (tid == 0) { s_prefix = 0u; s_rem = k; }
    __syncthreads();
    for (int pass = 0; pass < 4; ++pass) {
        hist[tid] = 0;
        __syncthreads();
        unsigned pref = s_prefix;
        int shift = 24 - 8 * pass;
        for (int p = tid; p < PP; p += 256) {
            unsigned u = __float_as_uint(v[p]);
            bool ok = (pass == 0) || ((u >> (shift + 8)) == pref);
            if (ok) atomicAdd(&hist[(u >> shift) & 255], 1);
        }
        __syncthreads();
        if (tid == 0) {
            int r = s_rem; int bin;
            for (bin = 255; bin > 0; --bin) {
                if (r <= hist[bin]) break;
                r -= hist[bin];
            }
            s_prefix = (pref << 8) | (unsigned)bin;
            s_rem = r;
        }
        __syncthreads();
    }
    unsigned tbits = s_prefix;
    float tval = __uint_as_float(tbits);
    int cg = 0; float sg = 0.0f;
    for (int p = tid; p < PP; p += 256) {
        float x = v[p];
        unsigned u = __float_as_uint(x);
        if (u > tbits) { cg++; sg += x; }
    }
    __shared__ float ssg[256]; __shared__ int scg[256];
    ssg[tid] = sg; scg[tid] = cg;
    __syncthreads();
    for (int s = 128; s > 0; s >>= 1) {
        if (tid < s) { ssg[tid] += ssg[tid + s]; scg[tid] += scg[tid + s]; }
        __syncthreads();
    }
    if (tid == 0) topk[b] = ssg[0] + (float)(k - scg[0]) * tval;
}

// K5: final reduction across batches -> (loss_l/N, loss_c/N).
__global__ void k_final(const float* __restrict__ stats, const int* __restrict__ nposa,
                        const float* __restrict__ topk, float* __restrict__ out) {
    int b = threadIdx.x;           // 64 threads = one wave
    float ll = stats[b * 2 + 0];
    float cc = stats[b * 2 + 1] + topk[b];
    int np = nposa[b];
    for (int s = 32; s > 0; s >>= 1) {
        ll += __shfl_down(ll, s);
        cc += __shfl_down(cc, s);
        np += __shfl_down(np, s);
    }
    if (b == 0) {
        float N = (float)np;
        out[0] = ll / N;
        out[1] = cc / N;
    }
}

extern "C" void kernel_launch(void* const* d_in, const int* in_sizes, int n_in,
                              void* d_out, int out_size, void* d_ws, size_t ws_size,
                              hipStream_t stream) {
    const float* arm_loc  = (const float*)d_in[0];
    const float* arm_conf = (const float*)d_in[1];
    // d_in[2], d_in[3] (odm_loc / odm_conf) are unused by the reference.
    const float* priors   = (const float*)d_in[4];
    const float* targets  = (const float*)d_in[5];
    float* out = (float*)d_out;

    char* w = (char*)d_ws;
    float* bto  = (float*)w;  w += sizeof(float) * (size_t)BB * PP;   // 8 MB
    int*   bti  = (int*)w;    w += sizeof(int)   * (size_t)BB * PP;   // 8 MB
    float* lcm  = (float*)w;  w += sizeof(float) * (size_t)BB * PP;   // 8 MB
    int*   bpi  = (int*)w;    w += sizeof(int)   * BB * OO;
    float* stats = (float*)w; w += sizeof(float) * BB * 2;
    int*   nposa = (int*)w;   w += sizeof(int)   * BB;
    float* topk  = (float*)w; w += sizeof(float) * BB;

    k_prior_best<<<dim3(PP / 256, BB), 256, 0, stream>>>(priors, targets, bto, bti);
    k_truth_best<<<dim3(OO, BB), 256, 0, stream>>>(priors, targets, bpi);
    k_force<<<BB, 64, 0, stream>>>(bpi, bto, bti);
    k_loss<<<BB, 256, 0, stream>>>(arm_loc, arm_conf, priors, targets, bto, bti,
                                   lcm, stats, nposa);
    k_topk<<<BB, 256, 0, stream>>>(lcm, nposa, topk);
    k_final<<<1, 64, 0, stream>>>(stats, nposa, topk, out);
}

// Round 2
// 467.643 us; speedup vs baseline: 1.2340x; 1.2340x over previous
//
#include <hip/hip_runtime.h>
#include <cstdint>

#pragma clang fp contract(off)

#define BB 64
#define PP 32768
#define OO 50
#define THRESH_F 0.5f
#define VAR0 0.1f
#define VAR1 0.2f
#define NEGPOS_I 3
#define SS 32            // k_loss splits per batch (1024 priors per block)

// IoU between truth (point form t0..t3) and prior point-form box.
__device__ __forceinline__ float iou_tp(float t0, float t1, float t2, float t3,
                                        float b0, float b1, float b2, float b3,
                                        float areaB) {
    float ltx = fmaxf(t0, b0), lty = fmaxf(t1, b1);
    float rbx = fminf(t2, b2), rby = fminf(t3, b3);
    float wx = fmaxf(rbx - ltx, 0.0f), wy = fmaxf(rby - lty, 0.0f);
    float inter = wx * wy;
    float areaA = (t2 - t0) * (t3 - t1);
    return inter / (areaA + areaB - inter);
}

// K1a: for every (b, p): max / first-argmax of IoU over the O truths.
__global__ void k_prior_best(const float* __restrict__ priors,
                             const float* __restrict__ targets,
                             float* __restrict__ bto, int* __restrict__ bti) {
    __shared__ float tr[OO * 4];
    int b = blockIdx.y;
    for (int i = threadIdx.x; i < OO * 4; i += blockDim.x) {
        int t = i >> 2, c = i & 3;
        tr[i] = targets[(size_t)(b * OO + t) * 5 + c];
    }
    __syncthreads();
    int p = blockIdx.x * blockDim.x + threadIdx.x;
    float4 pr = ((const float4*)priors)[p];
    float b0 = pr.x - pr.z * 0.5f, b1 = pr.y - pr.w * 0.5f;
    float b2 = pr.x + pr.z * 0.5f, b3 = pr.y + pr.w * 0.5f;
    float areaB = (b2 - b0) * (b3 - b1);
    float best = -1.0f; int bidx = 0;
    for (int t = 0; t < OO; ++t) {
        float v = iou_tp(tr[t * 4], tr[t * 4 + 1], tr[t * 4 + 2], tr[t * 4 + 3],
                         b0, b1, b2, b3, areaB);
        if (v > best) { best = v; bidx = t; }   // first-max: strict >
    }
    bto[(size_t)b * PP + p] = best;
    bti[(size_t)b * PP + p] = bidx;
}

// K1b: for every (b, t): argmax of IoU over the P priors (first index on ties).
__global__ void k_truth_best(const float* __restrict__ priors,
                             const float* __restrict__ targets,
                             int* __restrict__ bpi) {
    int b = blockIdx.y, t = blockIdx.x, tid = threadIdx.x;
    const float* tb = &targets[(size_t)(b * OO + t) * 5];
    float t0 = tb[0], t1 = tb[1], t2 = tb[2], t3 = tb[3];
    float best = -1.0f; int bidx = PP;
    for (int p = tid; p < PP; p += blockDim.x) {
        float4 pr = ((const float4*)priors)[p];
        float b0 = pr.x - pr.z * 0.5f, b1 = pr.y - pr.w * 0.5f;
        float b2 = pr.x + pr.z * 0.5f, b3 = pr.y + pr.w * 0.5f;
        float areaB = (b2 - b0) * (b3 - b1);
        float v = iou_tp(t0, t1, t2, t3, b0, b1, b2, b3, areaB);
        if (v > best || (v == best && p < bidx)) { best = v; bidx = p; }
    }
    __shared__ float sv[256]; __shared__ int si[256];
    sv[tid] = best; si[tid] = bidx;
    __syncthreads();
    for (int s = 128; s > 0; s >>= 1) {
        if (tid < s) {
            if (sv[tid + s] > sv[tid] ||
                (sv[tid + s] == sv[tid] && si[tid + s] < si[tid])) {
                sv[tid] = sv[tid + s]; si[tid] = si[tid + s];
            }
        }
        __syncthreads();
    }
    if (tid == 0) bpi[b * OO + t] = si[0];
}

// K2: forced match — sequential per batch, last write wins (mirrors jnp scatter).
__global__ void k_force(const int* __restrict__ bpi,
                        float* __restrict__ bto, int* __restrict__ bti) {
    int b = blockIdx.x;
    if (threadIdx.x == 0) {
        for (int j = 0; j < OO; ++j) {
            int p = bpi[b * OO + j];
            bto[(size_t)b * PP + p] = 2.0f;
            bti[(size_t)b * PP + p] = j;
        }
    }
}

// K3: grid (SS, BB); each block handles 1024 priors of one batch.
// Writes lcm (float4) and per-block partial {loss_l, sum_pos lc, num_pos}.
__global__ void k_loss(const float* __restrict__ arm_loc,
                       const float* __restrict__ arm_conf,
                       const float* __restrict__ priors,
                       const float* __restrict__ targets,
                       const float* __restrict__ bto, const int* __restrict__ bti,
                       float* __restrict__ lcm,
                       float* __restrict__ pll, float* __restrict__ pplc,
                       int* __restrict__ pnp) {
    int b = blockIdx.y, s = blockIdx.x, tid = threadIdx.x;
    int p = s * 1024 + tid * 4;
    size_t bp = (size_t)b * PP + p;

    float4 ov4 = ((const float4*)bto)[bp >> 2];
    int4   ti4 = ((const int4*)bti)[bp >> 2];
    float4 ca  = ((const float4*)arm_conf)[bp >> 1];
    float4 cb  = ((const float4*)arm_conf)[(bp >> 1) + 1];
    float ovs[4] = {ov4.x, ov4.y, ov4.z, ov4.w};
    int   tis[4] = {ti4.x, ti4.y, ti4.z, ti4.w};
    float cs[8]  = {ca.x, ca.y, ca.z, ca.w, cb.x, cb.y, cb.z, cb.w};

    float ll = 0.0f, plc = 0.0f; int np = 0;
    float outv[4];
    for (int c = 0; c < 4; ++c) {
        int ti = tis[c];
        const float* tb = &targets[(size_t)(b * OO + ti) * 5];
        int label = (tb[4] >= 0.0f) ? 1 : 0;
        int conf = (ovs[c] < THRESH_F) ? 0 : label;
        float c0 = cs[c * 2], c1 = cs[c * 2 + 1];
        float m = fmaxf(c0, c1);
        float lse = logf(expf(c0 - m) + expf(c1 - m)) + m;
        float picked = (conf == 1) ? c1 : c0;
        float lc = lse - picked;
        bool pos = conf > 0;
        outv[c] = pos ? 0.0f : lc;
        if (pos) {
            np++; plc += lc;
            float4 pr = ((const float4*)priors)[p + c];
            float gx = ((tb[0] + tb[2]) * 0.5f - pr.x) / (VAR0 * pr.z);
            float gy = ((tb[1] + tb[3]) * 0.5f - pr.y) / (VAR0 * pr.w);
            float gw = logf((tb[2] - tb[0]) / pr.z) / VAR1;
            float gh = logf((tb[3] - tb[1]) / pr.w) / VAR1;
            float g[4] = {gx, gy, gw, gh};
            float4 ld = ((const float4*)arm_loc)[bp + c];
            float lds_[4] = {ld.x, ld.y, ld.z, ld.w};
            for (int q = 0; q < 4; ++q) {
                float d = lds_[q] - g[q];
                float ad = fabsf(d);
                ll += (ad < 1.0f) ? 0.5f * d * d : ad - 0.5f;
            }
        }
    }
    ((float4*)lcm)[bp >> 2] = make_float4(outv[0], outv[1], outv[2], outv[3]);

    __shared__ float s1[256], s2[256]; __shared__ int s3[256];
    s1[tid] = ll; s2[tid] = plc; s3[tid] = np;
    __syncthreads();
    for (int st = 128; st > 0; st >>= 1) {
        if (tid < st) { s1[tid] += s1[tid + st]; s2[tid] += s2[tid + st]; s3[tid] += s3[tid + st]; }
        __syncthreads();
    }
    if (tid == 0) {
        pll[b * SS + s] = s1[0];
        pplc[b * SS + s] = s2[0];
        pnp[b * SS + s] = s3[0];
    }
}

// K4: per-batch exact top-k sum of lc_mine via 4x8-bit radix select on float
// bits (all values >= +0 so uint order == float order). 1024 threads, float4
// loads, wave-aggregated histogram atomics (values cluster in few bins).
__global__ void __launch_bounds__(1024)
k_topk(const float* __restrict__ lcm, const int* __restrict__ pnp,
       float* __restrict__ topk) {
    int b = blockIdx.x, tid = threadIdx.x;
    int lane = tid & 63, wid = tid >> 6;

    __shared__ int s_np;
    {
        __shared__ int rbuf[SS];
        if (tid < SS) rbuf[tid] = pnp[b * SS + tid];
        __syncthreads();
        if (tid == 0) { int t = 0; for (int i = 0; i < SS; ++i) t += rbuf[i]; s_np = t; }
        __syncthreads();
    }
    int np = s_np;
    int k = NEGPOS_I * np; if (k > PP - 1) k = PP - 1;
    if (k <= 0) { if (tid == 0) topk[b] = 0.0f; return; }

    const float4* v4 = (const float4*)(lcm + (size_t)b * PP);
    __shared__ int hist[4][256];
    __shared__ unsigned s_prefix; __shared__ int s_rem;
    if (tid == 0) { s_prefix = 0u; s_rem = k; }
    int hc = wid & 3;   // histogram copy for this wave

    for (int pass = 0; pass < 4; ++pass) {
        hist[tid >> 8][tid & 255] = 0;
        __syncthreads();
        unsigned pref = s_prefix;
        int shift = 24 - 8 * pass;
        for (int i = tid; i < PP / 4; i += 1024) {
            float4 x = v4[i];
            float xs[4] = {x.x, x.y, x.z, x.w};
            for (int c = 0; c < 4; ++c) {
                unsigned u = __float_as_uint(xs[c]);
                bool ok = (pass == 0) || ((u >> (shift + 8)) == pref);
                unsigned bin = (u >> shift) & 255u;
                // wave-aggregated atomic (match-any emulation)
                unsigned long long act = __ballot(ok);
                while (act) {
                    int leader = __ffsll((long long)act) - 1;
                    unsigned lb = (unsigned)__shfl((int)bin, leader);
                    unsigned long long same = __ballot(ok && bin == lb);
                    if (lane == leader) atomicAdd(&hist[hc][lb], (int)__popcll(same));
                    act &= ~same;
                }
            }
        }
        __syncthreads();
        if (tid < 256) {
            hist[0][tid] = hist[0][tid] + hist[1][tid] + hist[2][tid] + hist[3][tid];
        }
        __syncthreads();
        if (tid == 0) {
            int r = s_rem; int bin;
            for (bin = 255; bin > 0; --bin) {
                if (r <= hist[0][bin]) break;
                r -= hist[0][bin];
            }
            s_prefix = (pref << 8) | (unsigned)bin;
            s_rem = r;
        }
        __syncthreads();
    }
    unsigned tbits = s_prefix;
    float tval = __uint_as_float(tbits);

    int cg = 0; float sg = 0.0f;
    for (int i = tid; i < PP / 4; i += 1024) {
        float4 x = v4[i];
        float xs[4] = {x.x, x.y, x.z, x.w};
        for (int c = 0; c < 4; ++c) {
            unsigned u = __float_as_uint(xs[c]);
            if (u > tbits) { cg++; sg += xs[c]; }
        }
    }
    // wave reduce then LDS across 16 waves
    for (int s = 32; s > 0; s >>= 1) { sg += __shfl_down(sg, s); cg += __shfl_down(cg, s); }
    __shared__ float wsg[16]; __shared__ int wcg[16];
    if (lane == 0) { wsg[wid] = sg; wcg[wid] = cg; }
    __syncthreads();
    if (tid == 0) {
        float S = 0.0f; int C = 0;
        for (int w = 0; w < 16; ++w) { S += wsg[w]; C += wcg[w]; }
        topk[b] = S + (float)(k - C) * tval;
    }
}

// K5: final reduction across batches -> (loss_l/N, loss_c/N).
__global__ void k_final(const float* __restrict__ pll, const float* __restrict__ pplc,
                        const int* __restrict__ pnp, const float* __restrict__ topk,
                        float* __restrict__ out) {
    int b = threadIdx.x;           // 64 threads = one wave, one batch each
    float ll = 0.0f, plc = 0.0f; int np = 0;
    for (int s = 0; s < SS; ++s) {
        ll += pll[b * SS + s];
        plc += pplc[b * SS + s];
        np += pnp[b * SS + s];
    }
    float cc = plc + topk[b];
    for (int s = 32; s > 0; s >>= 1) {
        ll += __shfl_down(ll, s);
        cc += __shfl_down(cc, s);
        np += __shfl_down(np, s);
    }
    if (b == 0) {
        float N = (float)np;
        out[0] = ll / N;
        out[1] = cc / N;
    }
}

extern "C" void kernel_launch(void* const* d_in, const int* in_sizes, int n_in,
                              void* d_out, int out_size, void* d_ws, size_t ws_size,
                              hipStream_t stream) {
    const float* arm_loc  = (const float*)d_in[0];
    const float* arm_conf = (const float*)d_in[1];
    const float* priors   = (const float*)d_in[4];
    const float* targets  = (const float*)d_in[5];
    float* out = (float*)d_out;

    char* w = (char*)d_ws;
    float* bto  = (float*)w;  w += sizeof(float) * (size_t)BB * PP;   // 8 MB
    int*   bti  = (int*)w;    w += sizeof(int)   * (size_t)BB * PP;   // 8 MB
    float* lcm  = (float*)w;  w += sizeof(float) * (size_t)BB * PP;   // 8 MB
    int*   bpi  = (int*)w;    w += sizeof(int)   * BB * OO;
    float* pll  = (float*)w;  w += sizeof(float) * BB * SS;
    float* pplc = (float*)w;  w += sizeof(float) * BB * SS;
    int*   pnp  = (int*)w;    w += sizeof(int)   * BB * SS;
    float* topk = (float*)w;  w += sizeof(float) * BB;

    k_prior_best<<<dim3(PP / 256, BB), 256, 0, stream>>>(priors, targets, bto, bti);
    k_truth_best<<<dim3(OO, BB), 256, 0, stream>>>(priors, targets, bpi);
    k_force<<<BB, 64, 0, stream>>>(bpi, bto, bti);
    k_loss<<<dim3(SS, BB), 256, 0, stream>>>(arm_loc, arm_conf, priors, targets,
                                             bto, bti, lcm, pll, pplc, pnp);
    k_topk<<<BB, 1024, 0, stream>>>(lcm, pnp, topk);
    k_final<<<1, 64, 0, stream>>>(pll, pplc, pnp, topk, out);
}

// Round 3
// 282.857 us; speedup vs baseline: 2.0402x; 1.6533x over previous
//
#include <hip/hip_runtime.h>
#include <cstdint>

#pragma clang fp contract(off)

#define BB 64
#define PP 32768
#define OO 50
#define THRESH_F 0.5f
#define VAR0 0.1f
#define VAR1 0.2f
#define NEGPOS_I 3
#define SS 32            // k_loss splits per batch
#define T1 8             // priors per thread in k_match
#define NB0 2048         // pass-0 bins (bits 30:20)
#define NB12 1024        // pass-1/2 bins (10 bits each)

typedef unsigned long long u64;

// ---- K0: zero the atomically-accumulated region (hists + bpm) ----
__global__ void k_zero(float4* __restrict__ dst, int n4) {
    int i = blockIdx.x * blockDim.x + threadIdx.x;
    if (i < n4) dst[i] = make_float4(0.f, 0.f, 0.f, 0.f);
}

// ---- K1: fused matcher. Each thread owns T1 consecutive priors; loops the 50
// truths computing each IoU once: row-best (per prior, regs) + column-best
// (per truth, wave u64 max-reduce -> one global atomicMax per wave).
// Packing (iou_bits<<32)|(PP-p): max == max IoU with smallest p on ties.
__global__ void __launch_bounds__(256)
k_match(const float* __restrict__ priors, const float* __restrict__ targets,
        float* __restrict__ bto, int* __restrict__ bti, u64* __restrict__ bpm) {
    __shared__ float tr4[OO * 4];
    __shared__ float trA[OO];
    int b = blockIdx.y, tid = threadIdx.x;
    for (int i = tid; i < OO * 4; i += 256)
        tr4[i] = targets[(size_t)(b * OO + (i >> 2)) * 5 + (i & 3)];
    __syncthreads();
    if (tid < OO)
        trA[tid] = (tr4[tid*4+2] - tr4[tid*4]) * (tr4[tid*4+3] - tr4[tid*4+1]);
    __syncthreads();

    int p0 = blockIdx.x * (256 * T1) + tid * T1;
    float bx0[T1], by0[T1], bx1[T1], by1[T1], aB[T1];
    for (int j = 0; j < T1; ++j) {
        float4 pr = ((const float4*)priors)[p0 + j];
        bx0[j] = pr.x - pr.z * 0.5f; by0[j] = pr.y - pr.w * 0.5f;
        bx1[j] = pr.x + pr.z * 0.5f; by1[j] = pr.y + pr.w * 0.5f;
        aB[j] = (bx1[j] - bx0[j]) * (by1[j] - by0[j]);
    }
    float rbv[T1]; int rbi[T1];
    for (int j = 0; j < T1; ++j) { rbv[j] = -1.0f; rbi[j] = 0; }

    for (int t = 0; t < OO; ++t) {
        float t0 = tr4[t*4], t1v = tr4[t*4+1], t2 = tr4[t*4+2], t3 = tr4[t*4+3];
        float aA = trA[t];
        float cbv = -1.0f; int cbp = 0;
        for (int j = 0; j < T1; ++j) {
            float ltx = fmaxf(t0, bx0[j]), lty = fmaxf(t1v, by0[j]);
            float rbx = fminf(t2, bx1[j]), rby = fminf(t3, by1[j]);
            float wx = fmaxf(rbx - ltx, 0.f), wy = fmaxf(rby - lty, 0.f);
            float inter = wx * wy;
            float v = inter / (aA + aB[j] - inter);
            if (v > rbv[j]) { rbv[j] = v; rbi[j] = t; }   // row: first-max (strict >)
            if (v > cbv) { cbv = v; cbp = p0 + j; }       // col: smallest p on ties
        }
        u64 pk = ((u64)__float_as_uint(cbv) << 32) | (unsigned)(PP - cbp);
        for (int s = 32; s >= 1; s >>= 1) {
            u64 o = __shfl_xor(pk, s, 64);
            if (o > pk) pk = o;
        }
        if ((tid & 63) == 0) atomicMax(&bpm[b * OO + t], pk);
    }
    size_t bp = (size_t)b * PP + p0;
    ((float4*)bto)[bp >> 2]       = make_float4(rbv[0], rbv[1], rbv[2], rbv[3]);
    ((float4*)bto)[(bp >> 2) + 1] = make_float4(rbv[4], rbv[5], rbv[6], rbv[7]);
    ((int4*)bti)[bp >> 2]         = make_int4(rbi[0], rbi[1], rbi[2], rbi[3]);
    ((int4*)bti)[(bp >> 2) + 1]   = make_int4(rbi[4], rbi[5], rbi[6], rbi[7]);
}

// ---- K2: forced match — sequential per batch, last write wins ----
__global__ void k_force(const u64* __restrict__ bpm,
                        float* __restrict__ bto, int* __restrict__ bti) {
    __shared__ int pidx[OO];
    int b = blockIdx.x, tid = threadIdx.x;
    if (tid < OO) pidx[tid] = PP - (int)(unsigned)(bpm[b * OO + tid] & 0xFFFFFFFFull);
    __syncthreads();
    if (tid == 0) {
        for (int j = 0; j < OO; ++j) {
            int p = pidx[j];
            bto[(size_t)b * PP + p] = 2.0f;
            bti[(size_t)b * PP + p] = j;
        }
    }
}

// ---- K3: conf/encode/smooth-L1/lc; writes lcm + per-block partials ----
__global__ void __launch_bounds__(256)
k_loss(const float* __restrict__ arm_loc, const float* __restrict__ arm_conf,
       const float* __restrict__ priors, const float* __restrict__ targets,
       const float* __restrict__ bto, const int* __restrict__ bti,
       float* __restrict__ lcm, float* __restrict__ pll,
       float* __restrict__ pplc, int* __restrict__ pnp) {
    int b = blockIdx.y, s = blockIdx.x, tid = threadIdx.x;
    int p = s * 1024 + tid * 4;
    size_t bp = (size_t)b * PP + p;

    float4 ov4 = ((const float4*)bto)[bp >> 2];
    int4   ti4 = ((const int4*)bti)[bp >> 2];
    float4 ca  = ((const float4*)arm_conf)[bp >> 1];
    float4 cb  = ((const float4*)arm_conf)[(bp >> 1) + 1];
    float ovs[4] = {ov4.x, ov4.y, ov4.z, ov4.w};
    int   tis[4] = {ti4.x, ti4.y, ti4.z, ti4.w};
    float cs[8]  = {ca.x, ca.y, ca.z, ca.w, cb.x, cb.y, cb.z, cb.w};

    float ll = 0.0f, plc = 0.0f; int np = 0;
    float outv[4];
    for (int c = 0; c < 4; ++c) {
        int ti = tis[c];
        const float* tb = &targets[(size_t)(b * OO + ti) * 5];
        int label = (tb[4] >= 0.0f) ? 1 : 0;
        int conf = (ovs[c] < THRESH_F) ? 0 : label;
        float c0 = cs[c * 2], c1 = cs[c * 2 + 1];
        float m = fmaxf(c0, c1);
        float lse = logf(expf(c0 - m) + expf(c1 - m)) + m;
        float picked = (conf == 1) ? c1 : c0;
        float lc = lse - picked;
        bool pos = conf > 0;
        outv[c] = pos ? 0.0f : lc;
        if (pos) {
            np++; plc += lc;
            float4 pr = ((const float4*)priors)[p + c];
            float gx = ((tb[0] + tb[2]) * 0.5f - pr.x) / (VAR0 * pr.z);
            float gy = ((tb[1] + tb[3]) * 0.5f - pr.y) / (VAR0 * pr.w);
            float gw = logf((tb[2] - tb[0]) / pr.z) / VAR1;
            float gh = logf((tb[3] - tb[1]) / pr.w) / VAR1;
            float g[4] = {gx, gy, gw, gh};
            float4 ld = ((const float4*)arm_loc)[bp + c];
            float lds_[4] = {ld.x, ld.y, ld.z, ld.w};
            for (int q = 0; q < 4; ++q) {
                float d = lds_[q] - g[q];
                float ad = fabsf(d);
                ll += (ad < 1.0f) ? 0.5f * d * d : ad - 0.5f;
            }
        }
    }
    ((float4*)lcm)[bp >> 2] = make_float4(outv[0], outv[1], outv[2], outv[3]);

    __shared__ float s1[256], s2[256]; __shared__ int s3[256];
    s1[tid] = ll; s2[tid] = plc; s3[tid] = np;
    __syncthreads();
    for (int st = 128; st > 0; st >>= 1) {
        if (tid < st) { s1[tid] += s1[tid+st]; s2[tid] += s2[tid+st]; s3[tid] += s3[tid+st]; }
        __syncthreads();
    }
    if (tid == 0) {
        pll[s * BB + b] = s1[0];
        pplc[s * BB + b] = s2[0];
        pnp[s * BB + b] = s3[0];
    }
}

// ---- K4 hist: multi-block per-batch histogram (count + value sum) ----
template <int PASS>
__global__ void __launch_bounds__(256)
k_hist(const float* __restrict__ lcm, const unsigned* __restrict__ spre,
       int* __restrict__ Hc, float* __restrict__ Hs) {
    const int nbins = (PASS == 0) ? NB0 : NB12;
    __shared__ int hc[NB0]; __shared__ float hs[NB0];
    int b = blockIdx.y, tid = threadIdx.x;
    for (int i = tid; i < nbins; i += 256) { hc[i] = 0; hs[i] = 0.f; }
    __syncthreads();
    unsigned pref = (PASS == 0) ? 0u : spre[b];
    const float4* v4 = (const float4*)(lcm + (size_t)b * PP);
    int base = blockIdx.x * 1024;
    for (int i = 0; i < 4; ++i) {
        float4 x = v4[base + i * 256 + tid];
        float xs[4] = {x.x, x.y, x.z, x.w};
        for (int c = 0; c < 4; ++c) {
            unsigned u = __float_as_uint(xs[c]);
            bool ok; unsigned bin;
            if (PASS == 0)      { ok = true;               bin = u >> 20; }
            else if (PASS == 1) { ok = (u >> 20) == pref;  bin = (u >> 10) & 1023u; }
            else                { ok = (u >> 10) == pref;  bin = u & 1023u; }
            if (ok) { atomicAdd(&hc[bin], 1); atomicAdd(&hs[bin], xs[c]); }
        }
    }
    __syncthreads();
    for (int i = tid; i < nbins; i += 256) {
        int cv = hc[i];
        if (cv) {
            atomicAdd(&Hc[b * nbins + i], cv);
            atomicAdd(&Hs[b * nbins + i], hs[i]);
        }
    }
}

// ---- K4 scan: parallel suffix-scan of a batch histogram; selects the bin
// containing the k-th largest, accumulates sum/count of all higher bins. ----
__global__ void __launch_bounds__(256)
k_scan(const int* __restrict__ Hc, const float* __restrict__ Hs, int nbins,
       int pass, const int* __restrict__ pnp, unsigned* __restrict__ spre,
       int* __restrict__ srem, float* __restrict__ ssum,
       unsigned* __restrict__ stb) {
    int b = blockIdx.x, tid = threadIdx.x;
    int CH = nbins >> 8;
    const int* hc = Hc + b * nbins;
    const float* hs = Hs + b * nbins;
    __shared__ int sc[256]; __shared__ float sf[256];
    __shared__ int s_chunk; __shared__ int s_r; __shared__ float s_S;

    int c = 0; float f = 0.f;
    int base = tid * CH;
    for (int i = 0; i < CH; ++i) { c += hc[base + i]; f += hs[base + i]; }
    sc[tid] = c; sf[tid] = f;
    __syncthreads();
    // inclusive suffix sums via Hillis-Steele
    for (int off = 1; off < 256; off <<= 1) {
        int cv = (tid + off < 256) ? sc[tid + off] : 0;
        float fv = (tid + off < 256) ? sf[tid + off] : 0.f;
        __syncthreads();
        sc[tid] += cv; sf[tid] += fv;
        __syncthreads();
    }
    if (tid == 0) {
        int r; float S;
        if (pass == 0) {
            int np = 0;
            for (int i = 0; i < SS; ++i) np += pnp[i * BB + b];
            int k = NEGPOS_I * np; if (k > PP - 1) k = PP - 1;
            r = k; S = 0.f;
        } else { r = srem[b]; S = ssum[b]; }
        s_r = r; s_S = S;
    }
    __syncthreads();
    int r = s_r;
    int nxt = (tid == 255) ? 0 : sc[tid + 1];
    if (sc[tid] >= r && nxt < r) s_chunk = tid;
    __syncthreads();
    if (tid == 0) {
        int ch = s_chunk;
        int r2 = r - ((ch == 255) ? 0 : sc[ch + 1]);
        float S2 = s_S + ((ch == 255) ? 0.f : sf[ch + 1]);
        int binSel = ch * CH;
        for (int i = CH - 1; i >= 0; --i) {
            int bin = ch * CH + i;
            int cb = hc[bin];
            if (r2 <= cb) { binSel = bin; break; }
            r2 -= cb; S2 += hs[bin];
        }
        unsigned pref = (pass == 0) ? (unsigned)binSel
                                    : ((spre[b] << 10) | (unsigned)binSel);
        spre[b] = pref; srem[b] = r2; ssum[b] = S2;
        if (pass == 2) stb[b] = pref;
    }
}

// ---- K5: final reduction across batches -> (loss_l/N, loss_c/N) ----
__global__ void k_final(const float* __restrict__ pll, const float* __restrict__ pplc,
                        const int* __restrict__ pnp, const float* __restrict__ ssum,
                        const int* __restrict__ srem, const unsigned* __restrict__ stb,
                        float* __restrict__ out) {
    int b = threadIdx.x;          // 64 threads = one wave, one batch each
    float ll = 0.f, plc = 0.f; int np = 0;
    for (int s = 0; s < SS; ++s) {
        ll += pll[s * BB + b];
        plc += pplc[s * BB + b];
        np += pnp[s * BB + b];
    }
    float tval = __uint_as_float(stb[b]);
    float cc = plc + ssum[b] + (float)srem[b] * tval;
    for (int s = 32; s > 0; s >>= 1) {
        ll += __shfl_down(ll, s);
        cc += __shfl_down(cc, s);
        np += __shfl_down(np, s);
    }
    if (b == 0) {
        float N = (float)np;
        out[0] = ll / N;
        out[1] = cc / N;
    }
}

extern "C" void kernel_launch(void* const* d_in, const int* in_sizes, int n_in,
                              void* d_out, int out_size, void* d_ws, size_t ws_size,
                              hipStream_t stream) {
    const float* arm_loc  = (const float*)d_in[0];
    const float* arm_conf = (const float*)d_in[1];
    const float* priors   = (const float*)d_in[4];
    const float* targets  = (const float*)d_in[5];
    float* out = (float*)d_out;

    char* w = (char*)d_ws;
    float* bto = (float*)w;  w += sizeof(float) * (size_t)BB * PP;    // 8 MB
    int*   bti = (int*)w;    w += sizeof(int)   * (size_t)BB * PP;    // 8 MB
    float* lcm = (float*)w;  w += sizeof(float) * (size_t)BB * PP;    // 8 MB
    // ---- zeroed region (atomically accumulated) ----
    char* zbase = w;
    int*   Hc0 = (int*)w;    w += sizeof(int)   * BB * NB0;
    float* Hs0 = (float*)w;  w += sizeof(float) * BB * NB0;
    int*   Hc1 = (int*)w;    w += sizeof(int)   * BB * NB12;
    float* Hs1 = (float*)w;  w += sizeof(float) * BB * NB12;
    int*   Hc2 = (int*)w;    w += sizeof(int)   * BB * NB12;
    float* Hs2 = (float*)w;  w += sizeof(float) * BB * NB12;
    u64*   bpm = (u64*)w;    w += sizeof(u64)   * BB * OO;
    size_t zbytes = (size_t)(w - zbase);
    // ---- plain written-before-read region ----
    float* pll  = (float*)w; w += sizeof(float) * BB * SS;
    float* pplc = (float*)w; w += sizeof(float) * BB * SS;
    int*   pnp  = (int*)w;   w += sizeof(int)   * BB * SS;
    unsigned* spre = (unsigned*)w; w += sizeof(unsigned) * BB;
    int*      srem = (int*)w;      w += sizeof(int) * BB;
    float*    ssum = (float*)w;    w += sizeof(float) * BB;
    unsigned* stb  = (unsigned*)w; w += sizeof(unsigned) * BB;

    int n4 = (int)(zbytes / 16);
    k_zero<<<(n4 + 255) / 256, 256, 0, stream>>>((float4*)zbase, n4);
    k_match<<<dim3(PP / (256 * T1), BB), 256, 0, stream>>>(priors, targets, bto, bti, bpm);
    k_force<<<BB, 64, 0, stream>>>(bpm, bto, bti);
    k_loss<<<dim3(SS, BB), 256, 0, stream>>>(arm_loc, arm_conf, priors, targets,
                                             bto, bti, lcm, pll, pplc, pnp);
    k_hist<0><<<dim3(8, BB), 256, 0, stream>>>(lcm, spre, Hc0, Hs0);
    k_scan<<<BB, 256, 0, stream>>>(Hc0, Hs0, NB0, 0, pnp, spre, srem, ssum, stb);
    k_hist<1><<<dim3(8, BB), 256, 0, stream>>>(lcm, spre, Hc1, Hs1);
    k_scan<<<BB, 256, 0, stream>>>(Hc1, Hs1, NB12, 1, pnp, spre, srem, ssum, stb);
    k_hist<2><<<dim3(8, BB), 256, 0, stream>>>(lcm, spre, Hc2, Hs2);
    k_scan<<<BB, 256, 0, stream>>>(Hc2, Hs2, NB12, 2, pnp, spre, srem, ssum, stb);
    k_final<<<1, 64, 0, stream>>>(pll, pplc, pnp, ssum, srem, stb, out);
}